// Round 1
// 620.251 us; speedup vs baseline: 1.0139x; 1.0139x over previous
//
#include <hip/hip_runtime.h>
#include <cstdint>
#include <cstddef>

#define T_TOK 2048
#define HID   2048
#define INTER 1408
#define NEXP  8
#define NPAIR 6144   /* 2*T routed + T shared */
#define SLICE 2883584  /* 1408*2048 elems = one expert weight slice */
#define BKS   32     /* K-tile */

typedef __bf16 bf16x8 __attribute__((ext_vector_type(8)));
typedef float  floatx4 __attribute__((ext_vector_type(4)));

// ---- workspace layout (bytes) ----
static const size_t XB_OFF   = 0;                                   // bf16 x  [T,H]          8,388,608
static const size_t HM_OFF   = XB_OFF + (size_t)T_TOK * HID * 2;    // bf16 hmid [NPAIR,I]   17,301,504
static const size_t GB_OFF   = HM_OFF + (size_t)NPAIR * INTER * 2;  // bf16 gate [9][I][H]   51,904,512
static const size_t UB_OFF   = GB_OFF + (size_t)9 * SLICE * 2;      // bf16 up   [9][I][H]   51,904,512
static const size_t DB_OFF   = UB_OFF + (size_t)9 * SLICE * 2;      // bf16 down [9][H][I]   51,904,512
static const size_t TOK_OFF  = DB_OFF + (size_t)9 * SLICE * 2;      // int  tok [NPAIR]
static const size_t WGT_OFF  = TOK_OFF + (size_t)NPAIR * 4;         // f32  wgt [NPAIR]
static const size_t TE_OFF   = WGT_OFF + (size_t)NPAIR * 4;         // int  top2 expert ids [T,2]
static const size_t TW_OFF   = TE_OFF + (size_t)T_TOK * 2 * 4;      // f32  top2 weights [T,2]
static const size_t CTRL_OFF = TW_OFF + (size_t)T_TOK * 2 * 4;      // int  counts[16] offsets[16] fill[16]

static __device__ __forceinline__ unsigned short f2bf(float f) {
    unsigned u = __float_as_uint(f);
    u += 0x7fffu + ((u >> 16) & 1u);          // round-to-nearest-even
    return (unsigned short)(u >> 16);
}
static __device__ __forceinline__ unsigned pk2(float a, float b) {
    return (unsigned)f2bf(a) | ((unsigned)f2bf(b) << 16);
}
// async global -> LDS, 16B per lane; dest = lds base (wave-uniform) + lane*16B
static __device__ __forceinline__ void g2l16(const void* g, void* l) {
    __builtin_amdgcn_global_load_lds(
        (const __attribute__((address_space(1))) unsigned int*)g,
        (__attribute__((address_space(3))) unsigned int*)l, 16, 0, 0);
}

// ---------------- x -> bf16 ----------------
__global__ __launch_bounds__(256) void k_cvt_x(const float* __restrict__ x,
                                               unsigned short* __restrict__ xb) {
    int gid = blockIdx.x * 256 + threadIdx.x;          // 8 elems each
    const float4* src = (const float4*)x;
    float4 a = src[gid * 2], b = src[gid * 2 + 1];
    uint4 o;
    o.x = pk2(a.x, a.y); o.y = pk2(a.z, a.w);
    o.z = pk2(b.x, b.y); o.w = pk2(b.z, b.w);
    ((uint4*)xb)[gid] = o;
}

// ---------------- all weights -> bf16 (gate/up/down, experts + shared at slice 8) ----
__global__ __launch_bounds__(256) void k_cvt_w(const float* __restrict__ g,
                                               const float* __restrict__ u,
                                               const float* __restrict__ d,
                                               const float* __restrict__ sg,
                                               const float* __restrict__ su,
                                               const float* __restrict__ sd,
                                               unsigned short* __restrict__ gb,
                                               unsigned short* __restrict__ ub,
                                               unsigned short* __restrict__ db) {
    int sl = blockIdx.z;                 // 0..7 experts, 8 = shared
    const float* src;
    unsigned short* dst;
    if (blockIdx.y == 0) {
        src = (sl < 8) ? g + (size_t)sl * SLICE : sg;
        dst = gb + (size_t)sl * SLICE;
    } else if (blockIdx.y == 1) {
        src = (sl < 8) ? u + (size_t)sl * SLICE : su;
        dst = ub + (size_t)sl * SLICE;
    } else {
        src = (sl < 8) ? d + (size_t)sl * SLICE : sd;
        dst = db + (size_t)sl * SLICE;
    }
    int gid = blockIdx.x * 256 + threadIdx.x;          // 8 elems each, 1408 blocks exact
    const float4* s4 = (const float4*)src;
    float4 a = s4[gid * 2], b = s4[gid * 2 + 1];
    uint4 o;
    o.x = pk2(a.x, a.y); o.y = pk2(a.z, a.w);
    o.z = pk2(b.x, b.y); o.w = pk2(b.z, b.w);
    ((uint4*)dst)[gid] = o;
}

// ---------------- router (fp32 exact) ----------------
__global__ __launch_bounds__(256) void k_router(const float* __restrict__ x,
                                                const float* __restrict__ rw,
                                                int* __restrict__ te, float* __restrict__ tw,
                                                int* __restrict__ counts) {
    int wave = threadIdx.x >> 6, lane = threadIdx.x & 63;
    int t = blockIdx.x * 4 + wave;
    const float* xp = x + (size_t)t * HID;

    float acc[8];
#pragma unroll
    for (int e = 0; e < 8; ++e) acc[e] = 0.f;
    for (int i = lane; i < HID; i += 64) {
        float xv = xp[i];
#pragma unroll
        for (int e = 0; e < 8; ++e) acc[e] = fmaf(xv, rw[e * HID + i], acc[e]);
    }
#pragma unroll
    for (int e = 0; e < 8; ++e) {
        float v = acc[e];
        for (int s = 32; s; s >>= 1) v += __shfl_xor(v, s, 64);
        acc[e] = v;
    }
    float mx = acc[0];
#pragma unroll
    for (int e = 1; e < 8; ++e) mx = fmaxf(mx, acc[e]);
    float p[8];
#pragma unroll
    for (int e = 0; e < 8; ++e) p[e] = __expf(acc[e] - mx);
    int i1 = 0; float v1 = p[0];
#pragma unroll
    for (int e = 1; e < 8; ++e) if (p[e] > v1) { v1 = p[e]; i1 = e; }
    int i2 = -1; float v2 = -1.f;
#pragma unroll
    for (int e = 0; e < 8; ++e) if (e != i1 && p[e] > v2) { v2 = p[e]; i2 = e; }
    float inv = 1.f / (v1 + v2);
    if (lane == 0) {
        te[2 * t] = i1;     tw[2 * t] = v1 * inv;
        te[2 * t + 1] = i2; tw[2 * t + 1] = v2 * inv;
        atomicAdd(&counts[i1], 1);
        atomicAdd(&counts[i2], 1);
    }
}

// ---------------- offsets (prefix over 8 counts) ----------------
__global__ void k_offsets(int* __restrict__ ctrl) {
    if (threadIdx.x == 0) {
        int s = 0;
        for (int e = 0; e < 8; ++e) { ctrl[16 + e] = s; s += ctrl[e]; }
        ctrl[16 + 8] = s;      // == 2*T
        ctrl[8] = T_TOK;       // shared expert count
    }
}

// ---------------- scatter pair lists ----------------
__global__ __launch_bounds__(256) void k_scatter(const int* __restrict__ te,
                                                 const float* __restrict__ tw,
                                                 const int* __restrict__ offsets,
                                                 int* __restrict__ fill,
                                                 int* __restrict__ tok, float* __restrict__ wgt) {
    int t = blockIdx.x * 256 + threadIdx.x;
    if (t >= T_TOK) return;
#pragma unroll
    for (int k = 0; k < 2; ++k) {
        int e = te[2 * t + k];
        int slot = atomicAdd(&fill[e], 1);
        int pp = offsets[e] + slot;
        tok[pp] = t; wgt[pp] = tw[2 * t + k];
    }
    tok[2 * T_TOK + t] = t; wgt[2 * T_TOK + t] = 1.0f;   // shared expert region
}

// ---------------- GEMM1: hmid = silu(x@gateT) * (x@upT), gathered rows ----------------
// m97 structure: BM=128 BN=64 BK=32, 256 thr / 4 waves, global_load_lds staging, bf16 weights.
__global__ __launch_bounds__(256) void k_gemm1(const unsigned short* __restrict__ xb,
                                               const unsigned short* __restrict__ gwb,
                                               const unsigned short* __restrict__ uwb,
                                               const int* __restrict__ tok,
                                               const int* __restrict__ ctrl,
                                               unsigned short* __restrict__ hmid) {
    int e = blockIdx.z;
    int cnt = ctrl[e];
    int m0 = blockIdx.y * 128;
    if (m0 >= cnt) return;
    int off = ctrl[16 + e];
    int i0 = blockIdx.x * 64;
    const unsigned short* gw = gwb + (size_t)e * SLICE;
    const unsigned short* uw = uwb + (size_t)e * SLICE;

    __shared__ __align__(16) unsigned short As[128 * BKS];
    __shared__ __align__(16) unsigned short Bg[64 * BKS];
    __shared__ __align__(16) unsigned short Bu[64 * BKS];

    int tid = threadIdx.x;
    int lane = tid & 63, wave = tid >> 6;
    int lr = lane >> 2, lc = (lane & 3) * 8;     // 16 rows x 32 cols per wave-call

    // A: wave w stages rows [32w, 32w+32) in 2 calls of 16 rows
    int r0 = m0 + wave * 32 + lr;
    int ap0 = off + r0;       if (ap0 > NPAIR - 1) ap0 = NPAIR - 1;
    int ap1 = off + r0 + 16;  if (ap1 > NPAIR - 1) ap1 = NPAIR - 1;
    const unsigned short* a0 = xb + (size_t)tok[ap0] * HID + lc;
    const unsigned short* a1 = xb + (size_t)tok[ap1] * HID + lc;
    // B: wave w stages rows [16w, 16w+16)
    const unsigned short* bg = gw + (size_t)(i0 + wave * 16 + lr) * HID + lc;
    const unsigned short* bu = uw + (size_t)(i0 + wave * 16 + lr) * HID + lc;

    unsigned short* lA0 = &As[(wave * 32) * BKS];
    unsigned short* lA1 = &As[(wave * 32 + 16) * BKS];
    unsigned short* lBg = &Bg[(wave * 16) * BKS];
    unsigned short* lBu = &Bu[(wave * 16) * BKS];

    floatx4 accg[2][4], accu[2][4];
#pragma unroll
    for (int mi = 0; mi < 2; ++mi)
#pragma unroll
        for (int ni = 0; ni < 4; ++ni) {
            accg[mi][ni] = (floatx4){0.f, 0.f, 0.f, 0.f};
            accu[mi][ni] = (floatx4){0.f, 0.f, 0.f, 0.f};
        }

    int wm = wave * 32;
    int mrow = lane & 15, kq = (lane >> 4) * 8;

    for (int kt = 0; kt < HID / BKS; ++kt) {
        int k0 = kt * BKS;
        g2l16(a0 + k0, lA0);
        g2l16(a1 + k0, lA1);
        g2l16(bg + k0, lBg);
        g2l16(bu + k0, lBu);
        __syncthreads();                       // vmcnt(0) drain + all waves staged

        bf16x8 af[2];
#pragma unroll
        for (int mi = 0; mi < 2; ++mi)
            af[mi] = *(const bf16x8*)&As[(wm + mi * 16 + mrow) * BKS + kq];
#pragma unroll
        for (int ni = 0; ni < 4; ++ni) {
            bf16x8 bgv = *(const bf16x8*)&Bg[(ni * 16 + mrow) * BKS + kq];
            bf16x8 buv = *(const bf16x8*)&Bu[(ni * 16 + mrow) * BKS + kq];
#pragma unroll
            for (int mi = 0; mi < 2; ++mi) {
                accg[mi][ni] = __builtin_amdgcn_mfma_f32_16x16x32_bf16(af[mi], bgv, accg[mi][ni], 0, 0, 0);
                accu[mi][ni] = __builtin_amdgcn_mfma_f32_16x16x32_bf16(af[mi], buv, accu[mi][ni], 0, 0, 0);
            }
        }
        __syncthreads();                       // reads done before next overwrite
    }

    int quad = lane >> 4, col = lane & 15;
#pragma unroll
    for (int mi = 0; mi < 2; ++mi)
#pragma unroll
        for (int ni = 0; ni < 4; ++ni)
#pragma unroll
            for (int r = 0; r < 4; ++r) {
                int row = m0 + wm + mi * 16 + quad * 4 + r;
                if (row < cnt) {
                    float g = accg[mi][ni][r], u = accu[mi][ni][r];
                    float s = g / (1.f + __expf(-g));
                    hmid[(size_t)(off + row) * INTER + i0 + ni * 16 + col] = f2bf(s * u);
                }
            }
}

// ---------------- GEMM2: out[tok] += w * (hmid @ downT) ----------------
__global__ __launch_bounds__(256) void k_gemm2(const unsigned short* __restrict__ hmid,
                                               const unsigned short* __restrict__ dwb,
                                               const int* __restrict__ tok,
                                               const float* __restrict__ wgt,
                                               const int* __restrict__ ctrl,
                                               float* __restrict__ out) {
    int e = blockIdx.z;
    int cnt = ctrl[e];
    int m0 = blockIdx.y * 128;
    if (m0 >= cnt) return;
    int off = ctrl[16 + e];
    int n0 = blockIdx.x * 64;
    const unsigned short* dw = dwb + (size_t)e * SLICE;

    __shared__ __align__(16) unsigned short As[128 * BKS];
    __shared__ __align__(16) unsigned short Bd[64 * BKS];

    int tid = threadIdx.x;
    int lane = tid & 63, wave = tid >> 6;
    int lr = lane >> 2, lc = (lane & 3) * 8;

    int r0 = m0 + wave * 32 + lr;
    int ap0 = off + r0;       if (ap0 > NPAIR - 1) ap0 = NPAIR - 1;
    int ap1 = off + r0 + 16;  if (ap1 > NPAIR - 1) ap1 = NPAIR - 1;
    const unsigned short* a0 = hmid + (size_t)ap0 * INTER + lc;
    const unsigned short* a1 = hmid + (size_t)ap1 * INTER + lc;
    const unsigned short* bd = dw + (size_t)(n0 + wave * 16 + lr) * INTER + lc;

    unsigned short* lA0 = &As[(wave * 32) * BKS];
    unsigned short* lA1 = &As[(wave * 32 + 16) * BKS];
    unsigned short* lBd = &Bd[(wave * 16) * BKS];

    floatx4 acc[2][4];
#pragma unroll
    for (int mi = 0; mi < 2; ++mi)
#pragma unroll
        for (int ni = 0; ni < 4; ++ni) acc[mi][ni] = (floatx4){0.f, 0.f, 0.f, 0.f};

    int wm = wave * 32;
    int mrow = lane & 15, kq = (lane >> 4) * 8;

    for (int kt = 0; kt < INTER / BKS; ++kt) {
        int k0 = kt * BKS;
        g2l16(a0 + k0, lA0);
        g2l16(a1 + k0, lA1);
        g2l16(bd + k0, lBd);
        __syncthreads();

        bf16x8 af[2];
#pragma unroll
        for (int mi = 0; mi < 2; ++mi)
            af[mi] = *(const bf16x8*)&As[(wm + mi * 16 + mrow) * BKS + kq];
#pragma unroll
        for (int ni = 0; ni < 4; ++ni) {
            bf16x8 bv = *(const bf16x8*)&Bd[(ni * 16 + mrow) * BKS + kq];
#pragma unroll
            for (int mi = 0; mi < 2; ++mi)
                acc[mi][ni] = __builtin_amdgcn_mfma_f32_16x16x32_bf16(af[mi], bv, acc[mi][ni], 0, 0, 0);
        }
        __syncthreads();
    }

    int quad = lane >> 4, col = lane & 15;
#pragma unroll
    for (int mi = 0; mi < 2; ++mi)
#pragma unroll
        for (int r = 0; r < 4; ++r) {
            int row = m0 + wm + mi * 16 + quad * 4 + r;
            if (row < cnt) {
                int p = off + row;
                int t = tok[p];
                float w = wgt[p];
#pragma unroll
                for (int ni = 0; ni < 4; ++ni)
                    atomicAdd(&out[(size_t)t * HID + n0 + ni * 16 + col], w * acc[mi][ni][r]);
            }
        }
}

extern "C" void kernel_launch(void* const* d_in, const int* in_sizes, int n_in,
                              void* d_out, int out_size, void* d_ws, size_t ws_size,
                              hipStream_t stream) {
    const float* x        = (const float*)d_in[0];
    const float* router_w = (const float*)d_in[1];
    const float* gate_w   = (const float*)d_in[2];
    const float* up_w     = (const float*)d_in[3];
    const float* down_w   = (const float*)d_in[4];
    const float* sgate    = (const float*)d_in[5];
    const float* sup      = (const float*)d_in[6];
    const float* sdown    = (const float*)d_in[7];
    float* out = (float*)d_out;

    char* ws = (char*)d_ws;
    unsigned short* xb   = (unsigned short*)(ws + XB_OFF);
    unsigned short* hmid = (unsigned short*)(ws + HM_OFF);
    unsigned short* gwb  = (unsigned short*)(ws + GB_OFF);
    unsigned short* uwb  = (unsigned short*)(ws + UB_OFF);
    unsigned short* dwb  = (unsigned short*)(ws + DB_OFF);
    int*   tok  = (int*)(ws + TOK_OFF);
    float* wgt  = (float*)(ws + WGT_OFF);
    int*   te   = (int*)(ws + TE_OFF);
    float* tw   = (float*)(ws + TW_OFF);
    int*   ctrl = (int*)(ws + CTRL_OFF);   // counts[16] | offsets[16] | fill[16]

    hipMemsetAsync(ctrl, 0, 48 * sizeof(int), stream);
    hipMemsetAsync(out, 0, (size_t)T_TOK * HID * sizeof(float), stream);

    k_cvt_x  <<<(T_TOK * HID) / 8 / 256, 256, 0, stream>>>(x, xb);
    k_cvt_w  <<<dim3(SLICE / 8 / 256, 3, 9), 256, 0, stream>>>(gate_w, up_w, down_w,
                                                               sgate, sup, sdown, gwb, uwb, dwb);
    k_router <<<T_TOK / 4, 256, 0, stream>>>(x, router_w, te, tw, ctrl);
    k_offsets<<<1, 64, 0, stream>>>(ctrl);
    k_scatter<<<T_TOK / 256, 256, 0, stream>>>(te, tw, ctrl + 16, ctrl + 32, tok, wgt);

    k_gemm1<<<dim3(INTER / 64, 16, 9), 256, 0, stream>>>(xb, gwb, uwb, tok, ctrl, hmid);
    k_gemm2<<<dim3(HID / 64, 16, 9), 256, 0, stream>>>(hmid, dwb, tok, wgt, ctrl, out);
}